// Round 6
// baseline (12.436 us; speedup 1.0000x reference)
//
#include <hip/hip_runtime.h>

// Forward output of the reference == hard top-k0 binary mask (straight-through
// (hard-soft)+soft == hard exactly in fp32; top-k0 set of soft == top-k0 set
// of x since clip(x+nu) is monotone). Tie-break for exact fp32 duplicates:
// lowest index first (matches jax.lax.top_k).
//
// One 512-thread block (8 waves) per row; 8 keys/lane in registers.
// Radix select: 2 histogram passes (8 bits each) fix the top-16-bit prefix;
// survivors (T ~ 4 for random data) are compacted and finished with a 16-step
// ballot bit-select. Histogram fallback for adversarial T > 64 keeps exactness.
//
// vs r5: replica merge + select chains run on WAVE 0 ONLY (broadcast result
// via LDS) -> LDS merge traffic 128KB -> 16KB; replicas are per-wave-pair
// ((w<<1)|(lane&1)) -> no cross-wave atomic contention on the hot bin
// (sortable top byte = sign|exp[7:1]: ~29% of N(0,1) shares one byte).

#define DIM  4096
#define EPL  8              // elems per lane: 8 waves * 64 lanes * 8 = 4096
#define NC0  16             // pass-0 histogram replicas
#define CPAD 260            // replica stride (ints): 16B-aligned, bank-shifted

__device__ __forceinline__ void select_bin(const int4 h, const int lane, const int kr,
                                           int& chosen, int& cumG, int& T) {
    // h = this lane's 4 bins (bins 4*lane .. 4*lane+3). Finds bin containing
    // the kr-th largest, count strictly greater (cumG), and bin count (T).
    const int s3 = h.w, s2 = h.z + s3, s1 = h.y + s2, s0 = h.x + s1;
    int v = s0;
    #pragma unroll
    for (int off = 1; off < 64; off <<= 1) {
        int t = __shfl_down(v, off, 64);
        if (lane + off < 64) v += t;
    }
    const int inc = v - s0;                       // totals of lanes > l
    const int S0 = s0 + inc, S1 = s1 + inc, S2 = s2 + inc, S3 = s3 + inc;
    int ci, cg, Tl;
    if      (S3 >= kr) { ci = 3; cg = inc; Tl = h.w; }
    else if (S2 >= kr) { ci = 2; cg = S3;  Tl = h.z; }
    else if (S1 >= kr) { ci = 1; cg = S2;  Tl = h.y; }
    else               { ci = 0; cg = S1;  Tl = h.x; }
    const bool has = (S0 >= kr) && (inc < kr);    // exactly one lane true
    const unsigned long long m = __ballot(has);
    const int src = __ffsll((unsigned long long)m) - 1;
    chosen = __shfl((lane << 2) + ci, src, 64);
    cumG   = __shfl(cg, src, 64);
    T      = __shfl(Tl, src, 64);
}

__global__ void __launch_bounds__(512)
topk_mask_kernel(const float* __restrict__ x, const int* __restrict__ k0ptr,
                 float* __restrict__ out) {
    const int tid  = threadIdx.x;
    const int lane = tid & 63;
    const int w    = tid >> 6;                    // 0..7
    const int row  = blockIdx.x;

    const float4* xr4   = (const float4*)(x   + (size_t)row * DIM);
    float4*       outr4 = (float4*)      (out + (size_t)row * DIM);

    __shared__ __align__(16) int hist0[NC0 * CPAD];   // pass-0 replicas
    __shared__ __align__(16) int hist1[256];          // pass 1
    __shared__ __align__(16) int histf0[256];         // fallback byte 1
    __shared__ __align__(16) int histf1[256];         // fallback byte 0
    __shared__ int bc[3];                             // {kr, pfx, T} broadcast
    __shared__ unsigned int surv[64];
    __shared__ int scnt;
    __shared__ int wtie[8];

    const int k0 = k0ptr[0];                      // uniform scalar load

    // Wave w owns elements [512w, 512w+512); elem of u[4i+c] (i in 0..1) is
    // 512w + 256i + 4*lane + c -> lexicographic (w,i,lane,c) = ascending idx.
    const float4 f0 = xr4[(w << 7) + lane];
    const float4 f1 = xr4[(w << 7) + 64 + lane];

    // Zero LDS while loads are in flight.
    for (int t = tid; t < NC0 * CPAD; t += 512) hist0[t] = 0;
    if (tid < 256) { hist1[tid] = 0; histf0[tid] = 0; }
    else           { histf1[tid - 256] = 0; }
    if (tid == 0) scnt = 0;

    // fp32 -> sortable-ascending uint32 (registers, static indexing).
    unsigned int u[EPL];
#define MAP4(i, vv)                                                        \
    {                                                                      \
        unsigned int b0 = __float_as_uint((vv).x);                         \
        unsigned int b1 = __float_as_uint((vv).y);                         \
        unsigned int b2 = __float_as_uint((vv).z);                         \
        unsigned int b3 = __float_as_uint((vv).w);                         \
        u[4*(i)+0] = (b0 & 0x80000000u) ? ~b0 : (b0 | 0x80000000u);        \
        u[4*(i)+1] = (b1 & 0x80000000u) ? ~b1 : (b1 | 0x80000000u);        \
        u[4*(i)+2] = (b2 & 0x80000000u) ? ~b2 : (b2 | 0x80000000u);        \
        u[4*(i)+3] = (b3 & 0x80000000u) ? ~b3 : (b3 | 0x80000000u);        \
    }
    MAP4(0, f0) MAP4(1, f1)
#undef MAP4

    __syncthreads();                              // zeros visible

    // ---- pass 0: replicated histogram of top byte (replica per wave-pair) --
    const int c0 = ((w << 1) | (lane & 1)) * CPAD;
    #pragma unroll
    for (int j = 0; j < EPL; ++j)
        atomicAdd(&hist0[c0 + (u[j] >> 24)], 1);
    __syncthreads();

    // ---- select 0 on wave 0 only, broadcast via LDS ----
    if (w == 0) {
        int4 h; h.x = 0; h.y = 0; h.z = 0; h.w = 0;
        #pragma unroll
        for (int c = 0; c < NC0; ++c) {
            const int4 t = *(const int4*)&hist0[c * CPAD + (lane << 2)];
            h.x += t.x; h.y += t.y; h.z += t.z; h.w += t.w;
        }
        int chosen, cumG, T0;
        select_bin(h, lane, k0, chosen, cumG, T0);
        if (lane == 0) { bc[0] = k0 - cumG; bc[1] = (int)(((unsigned)chosen) << 24); }
    }
    __syncthreads();
    int kr = bc[0];
    unsigned int pfx = (unsigned int)bc[1];

    // ---- pass 1: byte 2 among survivors (sparse -> single copy) ----
    #pragma unroll
    for (int j = 0; j < EPL; ++j)
        if ((u[j] & 0xFF000000u) == pfx)
            atomicAdd(&hist1[(u[j] >> 16) & 255u], 1);
    __syncthreads();
    if (w == 0) {
        const int4 h = *(const int4*)&hist1[lane << 2];
        int chosen, cumG, T1;
        select_bin(h, lane, kr, chosen, cumG, T1);
        if (lane == 0) {
            bc[0] = kr - cumG;
            bc[1] = (int)(pfx | (((unsigned)chosen) << 16));
            bc[2] = T1;
        }
    }
    __syncthreads();
    kr  = bc[0];
    pfx = (unsigned int)bc[1];
    int T = bc[2];

    unsigned int thr;
    if (T <= 64) {
        // ---- common path: compact survivors, ballot bit-select low 16 bits --
        #pragma unroll
        for (int j = 0; j < EPL; ++j)
            if ((u[j] & 0xFFFF0000u) == pfx) {
                const int slot = atomicAdd(&scnt, 1);
                surv[slot] = u[j];
            }
        __syncthreads();
        // Every wave runs this redundantly on identical data (no LDS except
        // the 256B surv read) -> no extra barrier/broadcast needed.
        const unsigned int v = (lane < T) ? surv[lane] : 0u;
        bool act = (lane < T);
        #pragma unroll
        for (int b = 15; b >= 0; --b) {
            const unsigned int bit = (v >> b) & 1u;
            const unsigned long long m1 = __ballot(act && (bit != 0u));
            const int c = __popcll(m1);
            const bool ge = (c >= kr);
            act = act && (bit == (ge ? 1u : 0u));
            if (!ge) kr -= c;
        }
        const unsigned long long ma = __ballot(act);
        T   = __popcll(ma);
        thr = __shfl(v, __ffsll((unsigned long long)ma) - 1, 64);
    } else {
        // ---- fallback (adversarial): histogram passes for bytes 1 and 0 ----
        #pragma unroll
        for (int j = 0; j < EPL; ++j)
            if ((u[j] & 0xFFFF0000u) == pfx)
                atomicAdd(&histf0[(u[j] >> 8) & 255u], 1);
        __syncthreads();
        if (w == 0) {
            const int4 h = *(const int4*)&histf0[lane << 2];
            int chosen, cumG, Tx;
            select_bin(h, lane, kr, chosen, cumG, Tx);
            if (lane == 0) {
                bc[0] = kr - cumG;
                bc[1] = (int)(pfx | (((unsigned)chosen) << 8));
            }
        }
        __syncthreads();
        kr  = bc[0];
        pfx = (unsigned int)bc[1];

        #pragma unroll
        for (int j = 0; j < EPL; ++j)
            if ((u[j] & 0xFFFFFF00u) == pfx)
                atomicAdd(&histf1[u[j] & 255u], 1);
        __syncthreads();
        if (w == 0) {
            const int4 h = *(const int4*)&histf1[lane << 2];
            int chosen, cumG, Tx;
            select_bin(h, lane, kr, chosen, cumG, Tx);
            if (lane == 0) {
                bc[0] = kr - cumG;
                bc[1] = (int)(pfx | (unsigned)chosen);
                bc[2] = Tx;
            }
        }
        __syncthreads();
        kr  = bc[0];
        thr = (unsigned int)bc[1];
        T   = bc[2];
    }
    // thr = k-th largest key; kr = ties to select; T = total ties (uniform).

    if (kr == T) {
        // All threshold ties selected: pure >= mask from registers.
        #pragma unroll
        for (int i = 0; i < 2; ++i) {
            float4 o;
            o.x = (u[4*i+0] >= thr) ? 1.0f : 0.0f;
            o.y = (u[4*i+1] >= thr) ? 1.0f : 0.0f;
            o.z = (u[4*i+2] >= thr) ? 1.0f : 0.0f;
            o.w = (u[4*i+3] >= thr) ? 1.0f : 0.0f;
            outr4[(w << 7) + (i << 6) + lane] = o;
        }
    } else {
        // Rare: rank exact ties in ascending global index order.
        int eqtot = 0;
        #pragma unroll
        for (int j = 0; j < EPL; ++j) eqtot += (u[j] == thr) ? 1 : 0;
        int vv = eqtot;
        #pragma unroll
        for (int off = 1; off < 64; off <<= 1) {
            int t = __shfl_up(vv, off, 64);
            if (lane >= off) vv += t;
        }
        if (lane == 63) wtie[w] = vv;             // per-wave tie totals
        __syncthreads();
        int base = 0;
        #pragma unroll
        for (int ww = 0; ww < 8; ++ww) if (ww < w) base += wtie[ww];

        #pragma unroll
        for (int i = 0; i < 2; ++i) {
            const int e0 = (u[4*i+0] == thr) ? 1 : 0;
            const int e1 = (u[4*i+1] == thr) ? 1 : 0;
            const int e2 = (u[4*i+2] == thr) ? 1 : 0;
            const int e3 = (u[4*i+3] == thr) ? 1 : 0;
            const int ti = e0 + e1 + e2 + e3;
            int vi = ti;
            #pragma unroll
            for (int off = 1; off < 64; off <<= 1) {
                int t = __shfl_up(vi, off, 64);
                if (lane >= off) vi += t;
            }
            int r = base + (vi - ti);             // ties before my first one
            const int tot = __shfl(vi, 63, 64);   // wave ties in this i-group
            float4 o;
            o.x = (u[4*i+0] > thr) ? 1.0f : ((e0 && r < kr) ? 1.0f : 0.0f); r += e0;
            o.y = (u[4*i+1] > thr) ? 1.0f : ((e1 && r < kr) ? 1.0f : 0.0f); r += e1;
            o.z = (u[4*i+2] > thr) ? 1.0f : ((e2 && r < kr) ? 1.0f : 0.0f); r += e2;
            o.w = (u[4*i+3] > thr) ? 1.0f : ((e3 && r < kr) ? 1.0f : 0.0f); r += e3;
            outr4[(w << 7) + (i << 6) + lane] = o;
            base += tot;
        }
    }
}

extern "C" void kernel_launch(void* const* d_in, const int* in_sizes, int n_in,
                              void* d_out, int out_size, void* d_ws, size_t ws_size,
                              hipStream_t stream) {
    const float* x   = (const float*)d_in[0];
    // d_in[1] = k vector [bs] (unused: forward mask depends only on k0)
    const int*   k0  = (const int*)d_in[2];
    float*       out = (float*)d_out;

    const int bs = in_sizes[1];                   // dim == 4096 (reference)
    topk_mask_kernel<<<bs, 512, 0, stream>>>(x, k0, out);
}